// Round 5
// baseline (2641.180 us; speedup 1.0000x reference)
//
#include <hip/hip_runtime.h>
#include <stdint.h>

#define NROWS 32768
#define DDIM  512
#define KDIM  512

__device__ __forceinline__ float b2f(unsigned short u) {
  return __uint_as_float(((unsigned int)u) << 16);
}
__device__ __forceinline__ unsigned short f2bf(float f) {
  unsigned int u = __float_as_uint(f);
  u += 0x7FFFu + ((u >> 16) & 1u);   // round-to-nearest-even
  return (unsigned short)(u >> 16);
}
__device__ __forceinline__ float dev_load(const float* p) {
  return __hip_atomic_load(p, __ATOMIC_RELAXED, __HIP_MEMORY_SCOPE_AGENT);
}

typedef __attribute__((ext_vector_type(8))) short bf16x8;
typedef __attribute__((ext_vector_type(4))) float f32x4;

// ---------------------------------------------------------------------------
// prep: row inverse-norms for z1/z2 (rows 0..65535) and normalized bf16 weight
// ---------------------------------------------------------------------------
__global__ __launch_bounds__(256) void prep_kernel(
    const float* __restrict__ z1, const float* __restrict__ z2,
    const float* __restrict__ w, float* __restrict__ rnorm,
    unsigned short* __restrict__ wnb) {
  const int tid = threadIdx.x;
  const int wv = tid >> 6, ln = tid & 63;
  const int row = blockIdx.x * 4 + wv;   // 0..66047
  const float* src;
  if (row < NROWS)        src = z1 + (size_t)row * DDIM;
  else if (row < 2*NROWS) src = z2 + (size_t)(row - NROWS) * DDIM;
  else                    src = w  + (size_t)(row - 2*NROWS) * DDIM;
  float4 v0 = ((const float4*)src)[ln*2];
  float4 v1 = ((const float4*)src)[ln*2+1];
  float ss = v0.x*v0.x + v0.y*v0.y + v0.z*v0.z + v0.w*v0.w
           + v1.x*v1.x + v1.y*v1.y + v1.z*v1.z + v1.w*v1.w;
  #pragma unroll
  for (int off = 1; off < 64; off <<= 1) ss += __shfl_xor(ss, off);
  float rn = 1.0f / fmaxf(sqrtf(ss), 1e-12f);
  if (row < 2*NROWS) {
    if (ln == 0) rnorm[row] = rn;
  } else {
    int r = row - 2*NROWS;
    ushort4 o0 = make_ushort4(f2bf(v0.x*rn), f2bf(v0.y*rn), f2bf(v0.z*rn), f2bf(v0.w*rn));
    ushort4 o1 = make_ushort4(f2bf(v1.x*rn), f2bf(v1.y*rn), f2bf(v1.z*rn), f2bf(v1.w*rn));
    ushort4* dst = (ushort4*)(wnb + (size_t)r*DDIM + ln*8);
    dst[0] = o0; dst[1] = o1;
  }
}

// ---------------------------------------------------------------------------
// initvecs: zero the 20 column-sum buffers (T[20][2*512]), the barrier
// counter, and the output
// ---------------------------------------------------------------------------
__global__ void initvecs_kernel(float* __restrict__ T, float* __restrict__ out,
                                unsigned int* __restrict__ bar) {
  int i = blockIdx.x * 256 + threadIdx.x;
  if (i < 20 * 1024) T[i] = 0.f;
  if (i == 0) { out[0] = 0.f; bar[0] = 0u; }
}

// ---------------------------------------------------------------------------
// gemm: zc[r,c] = sum_d (z[r,d]*rnorm[r]) * wnb[c,d]   (bf16 MFMA, A*B^T)
// 128x128 tile, BK=32, 4 waves each 64x64 via 4x4 of 16x16x32 MFMAs
// ---------------------------------------------------------------------------
__global__ __launch_bounds__(256) void gemm_kernel(
    const float* __restrict__ z1, const float* __restrict__ z2,
    const float* __restrict__ rnorm, const unsigned short* __restrict__ wnb,
    unsigned short* __restrict__ zc) {
  constexpr int LDT = 40;   // padded LDS stride (elements): 80B rows, 16B aligned
  __shared__ unsigned short As[128 * LDT];
  __shared__ unsigned short Bs[128 * LDT];
  const int tid = threadIdx.x;
  const int colBase = blockIdx.x * 128;
  const int rowBase = blockIdx.y * 128;
  const float* Aptr = (rowBase < NROWS) ? (z1 + (size_t)rowBase * DDIM)
                                        : (z2 + (size_t)(rowBase - NROWS) * DDIM);
  const int wv = tid >> 6, ln = tid & 63;
  const int wm = wv & 1, wn = wv >> 1;
  const int lrow = ln & 15, quad = ln >> 4;

  f32x4 acc[4][4] = {};

  for (int k0 = 0; k0 < DDIM; k0 += 32) {
    // stage A (fp32 -> normalized bf16): 128 rows x 32 k
    #pragma unroll
    for (int i = 0; i < 4; i++) {
      int idx = i * 256 + tid;            // 0..1023
      int r = idx >> 3;                   // 0..127
      int kk = (idx & 7) * 4;             // 0..28
      float4 v = *(const float4*)(Aptr + (size_t)r * DDIM + k0 + kk);
      float rn = rnorm[rowBase + r];
      ushort4 o = make_ushort4(f2bf(v.x*rn), f2bf(v.y*rn), f2bf(v.z*rn), f2bf(v.w*rn));
      *(ushort4*)(&As[r * LDT + kk]) = o;
    }
    // stage B (bf16 weight): 128 rows x 32 k
    #pragma unroll
    for (int i = 0; i < 2; i++) {
      int idx = i * 256 + tid;            // 0..511
      int r = idx >> 2;                   // 0..127
      int kk = (idx & 3) * 8;             // 0..24
      float4 v = *(const float4*)(wnb + (size_t)(colBase + r) * DDIM + k0 + kk);
      *(float4*)(&Bs[r * LDT + kk]) = v;
    }
    __syncthreads();
    bf16x8 af[4], bfr[4];
    #pragma unroll
    for (int mi = 0; mi < 4; mi++)
      af[mi] = *(const bf16x8*)(&As[(64*wm + 16*mi + lrow) * LDT + quad*8]);
    #pragma unroll
    for (int ni = 0; ni < 4; ni++)
      bfr[ni] = *(const bf16x8*)(&Bs[(64*wn + 16*ni + lrow) * LDT + quad*8]);
    #pragma unroll
    for (int mi = 0; mi < 4; mi++)
      #pragma unroll
      for (int ni = 0; ni < 4; ni++)
        acc[mi][ni] = __builtin_amdgcn_mfma_f32_16x16x32_bf16(
            af[mi], bfr[ni], acc[mi][ni], 0, 0, 0);
    __syncthreads();
  }
  // epilogue: C/D layout col=lane&15, row=(lane>>4)*4+reg
  #pragma unroll
  for (int mi = 0; mi < 4; mi++)
    #pragma unroll
    for (int ni = 0; ni < 4; ni++)
      #pragma unroll
      for (int r = 0; r < 4; r++) {
        size_t grow = (size_t)rowBase + 64*wm + 16*mi + quad*4 + r;
        int gcol = colBase + 64*wn + 16*ni + lrow;
        zc[grow * KDIM + gcol] = f2bf(acc[mi][ni][r]);
      }
}

// ---------------------------------------------------------------------------
// inline grid barrier: monotonic device-scope counter, no function call.
// ---------------------------------------------------------------------------
__device__ __forceinline__ void grid_barrier(unsigned int* bar, unsigned int target) {
  __threadfence();          // drain this thread's global writes (incl. atomics)
  __syncthreads();          // all 1024 threads of the block have fenced
  if (threadIdx.x == 0) {
    __hip_atomic_fetch_add(bar, 1u, __ATOMIC_RELEASE, __HIP_MEMORY_SCOPE_AGENT);
    while (__hip_atomic_load(bar, __ATOMIC_ACQUIRE, __HIP_MEMORY_SCOPE_AGENT) < target) {
      __builtin_amdgcn_s_sleep(1);
    }
  }
  __syncthreads();
}

// ---------------------------------------------------------------------------
// sink: fused 20-iteration sinkhorn + loss, single cooperative kernel.
// 256 blocks x 1024 threads (16 waves, 1 block/CU, co-resident by
// cooperative launch). Each wave holds 8 rows of BOTH matrices in registers
// (8 x bf16x8 x 2 = 64 VGPRs of data); lane ln owns cols ln*8..ln*8+7.
//
// Register-residency enforcement (rounds 1-4 all failed to get it):
//  (a) amdgpu_waves_per_eu(4,4): pins allocator target AND cap at exactly
//      4 waves/EU (1 block/CU, 128-VGPR budget). Plain __launch_bounds__
//      min-waves only sets the cap; the allocator still TARGETED 8 waves/EU
//      -> 64-VGPR budget -> 1.4 GB of spill/remat traffic.
//  (b) asm-opacity on d1/d2 after the initial load: zc is const __restrict__,
//      so the compiler legally rematerialized the "persistent" tile by
//      re-loading it every epoch (FETCH = 67 MB x ~18). An empty
//      asm volatile("":"+v"(x)) makes each value the result of an opaque
//      asm -- not re-derivable from memory, must stay live in registers.
// ---------------------------------------------------------------------------
__global__ __launch_bounds__(1024)
__attribute__((amdgpu_waves_per_eu(4, 4)))
void sink_kernel(
    const unsigned short* __restrict__ zc,
    float* __restrict__ T, float* __restrict__ out,
    unsigned int* __restrict__ bar) {
  __shared__ float red[16 * 1024];
  const int tid = threadIdx.x;
  const int wv = tid >> 6, ln = tid & 63;
  const int col0 = ln * 8;
  const size_t row0 = (size_t)blockIdx.x * 128 + (size_t)wv * 8;

  // load 8 rows of each matrix into registers (read zc exactly once)
  bf16x8 d1[8], d2[8];
  #pragma unroll
  for (int r = 0; r < 8; r++) {
    d1[r] = *(const bf16x8*)(zc + (row0 + r) * KDIM + col0);
    d2[r] = *(const bf16x8*)(zc + (row0 + r + (size_t)NROWS) * KDIM + col0);
  }
  // opacity: forbid rematerialization-from-global of the resident tile
  #pragma unroll
  for (int r = 0; r < 8; r++) {
    asm volatile("" : "+v"(d1[r]));
    asm volatile("" : "+v"(d2[r]));
  }

  #pragma unroll 1
  for (int it = 0; it < 20; it++) {
    const float* Tp = T + (size_t)(it - 1) * 1024;
    // ---- matrix 1 ----
    {
      float a[8];
      if (it > 0) {
        #pragma unroll
        for (int j = 0; j < 8; j++) a[j] = 1.0f / (512.0f * dev_load(Tp + col0 + j));
      }
      float acc[8] = {0,0,0,0,0,0,0,0};
      #pragma unroll
      for (int r = 0; r < 8; r++) {
        float e[8];
        #pragma unroll
        for (int j = 0; j < 8; j++) e[j] = __expf(b2f((unsigned short)d1[r][j]) * 20.f);
        if (it > 0) {
          float part = e[0]*a[0]+e[1]*a[1]+e[2]*a[2]+e[3]*a[3]
                     + e[4]*a[4]+e[5]*a[5]+e[6]*a[6]+e[7]*a[7];
          #pragma unroll
          for (int off = 1; off < 64; off <<= 1) part += __shfl_xor(part, off);
          float bb = 1.0f / (32768.0f * part);
          #pragma unroll
          for (int j = 0; j < 8; j++) acc[j] += e[j] * bb;
        } else {
          #pragma unroll
          for (int j = 0; j < 8; j++) acc[j] += e[j];
        }
      }
      #pragma unroll
      for (int j = 0; j < 8; j++) red[wv*1024 + col0 + j] = acc[j];
    }
    // ---- matrix 2 ----
    {
      float a[8];
      if (it > 0) {
        #pragma unroll
        for (int j = 0; j < 8; j++) a[j] = 1.0f / (512.0f * dev_load(Tp + 512 + col0 + j));
      }
      float acc[8] = {0,0,0,0,0,0,0,0};
      #pragma unroll
      for (int r = 0; r < 8; r++) {
        float e[8];
        #pragma unroll
        for (int j = 0; j < 8; j++) e[j] = __expf(b2f((unsigned short)d2[r][j]) * 20.f);
        if (it > 0) {
          float part = e[0]*a[0]+e[1]*a[1]+e[2]*a[2]+e[3]*a[3]
                     + e[4]*a[4]+e[5]*a[5]+e[6]*a[6]+e[7]*a[7];
          #pragma unroll
          for (int off = 1; off < 64; off <<= 1) part += __shfl_xor(part, off);
          float bb = 1.0f / (32768.0f * part);
          #pragma unroll
          for (int j = 0; j < 8; j++) acc[j] += e[j] * bb;
        } else {
          #pragma unroll
          for (int j = 0; j < 8; j++) acc[j] += e[j];
        }
      }
      #pragma unroll
      for (int j = 0; j < 8; j++) red[wv*1024 + 512 + col0 + j] = acc[j];
    }
    // block reduce (16 waves) then one atomic per column per block
    __syncthreads();
    float s = 0.f;
    #pragma unroll
    for (int w = 0; w < 16; w++) s += red[w*1024 + tid];
    float* Tn = T + (size_t)it * 1024;
    unsafeAtomicAdd(&Tn[tid], s);
    grid_barrier(bar, 256u * (unsigned int)(it + 1));
  }

  // ---- fused loss using T19 (b2f inlined per use: keeps peak VGPR < 128) ----
  {
    const float* Tl = T + (size_t)19 * 1024;
    float a1[8], a2[8];
    #pragma unroll
    for (int j = 0; j < 8; j++) {
      a1[j] = 1.0f / (512.0f * dev_load(Tl + col0 + j));
      a2[j] = 1.0f / (512.0f * dev_load(Tl + 512 + col0 + j));
    }
    const float invTau = 1.0f / 0.3f;
    float part = 0.f;
    #pragma unroll 1
    for (int r = 0; r < 8; r++) {
      float m1 = -1e30f, m2 = -1e30f;
      #pragma unroll
      for (int j = 0; j < 8; j++) {
        m1 = fmaxf(m1, b2f((unsigned short)d1[r][j]));
        m2 = fmaxf(m2, b2f((unsigned short)d2[r][j]));
      }
      #pragma unroll
      for (int off = 1; off < 64; off <<= 1) {
        m1 = fmaxf(m1, __shfl_xor(m1, off));
        m2 = fmaxf(m2, __shfl_xor(m2, off));
      }
      float se1 = 0.f, se2 = 0.f;
      #pragma unroll
      for (int j = 0; j < 8; j++) {
        se1 += __expf((b2f((unsigned short)d1[r][j]) - m1) * invTau);
        se2 += __expf((b2f((unsigned short)d2[r][j]) - m2) * invTau);
      }
      #pragma unroll
      for (int off = 1; off < 64; off <<= 1) {
        se1 += __shfl_xor(se1, off);
        se2 += __shfl_xor(se2, off);
      }
      float ls1 = m1 * invTau + __logf(se1);
      float ls2 = m2 * invTau + __logf(se2);
      float s1 = 0.f, n1 = 0.f, s2 = 0.f, n2 = 0.f;
      #pragma unroll
      for (int j = 0; j < 8; j++) {
        float zf1 = b2f((unsigned short)d1[r][j]);
        float zf2 = b2f((unsigned short)d2[r][j]);
        float e1 = __expf(zf1 * 20.f) * a1[j];
        s1 += e1; n1 += e1 * (zf2 * invTau - ls2);
        float e2 = __expf(zf2 * 20.f) * a2[j];
        s2 += e2; n2 += e2 * (zf1 * invTau - ls1);
      }
      #pragma unroll
      for (int off = 1; off < 64; off <<= 1) {
        s1 += __shfl_xor(s1, off); n1 += __shfl_xor(n1, off);
        s2 += __shfl_xor(s2, off); n2 += __shfl_xor(n2, off);
      }
      part += n1 / s1 + n2 / s2;
    }
    if (ln == 0) red[wv] = part;
    __syncthreads();
    if (tid == 0) {
      float s = 0.f;
      #pragma unroll
      for (int w = 0; w < 16; w++) s += red[w];
      unsafeAtomicAdd(out, -s * (1.0f / 32768.0f));
    }
  }
}

// ---------------------------------------------------------------------------
extern "C" void kernel_launch(void* const* d_in, const int* in_sizes, int n_in,
                              void* d_out, int out_size, void* d_ws, size_t ws_size,
                              hipStream_t stream) {
  (void)in_sizes; (void)n_in; (void)out_size; (void)ws_size;
  const float* z1 = (const float*)d_in[0];
  const float* z2 = (const float*)d_in[1];
  const float* w  = (const float*)d_in[2];
  float* out = (float*)d_out;
  char* ws = (char*)d_ws;
  // workspace layout
  unsigned short* zc    = (unsigned short*)ws;                         // 67,108,864 B
  float*          rnorm = (float*)(ws + (size_t)67108864);             //    262,144 B
  unsigned short* wnb   = (unsigned short*)(ws + (size_t)67371008);    //    524,288 B
  float*          T     = (float*)(ws + (size_t)67895296);             //     81,920 B
  unsigned int*   bar   = (unsigned int*)(ws + (size_t)67977216);      //         64 B

  hipLaunchKernelGGL(prep_kernel, dim3(16512), dim3(256), 0, stream, z1, z2, w, rnorm, wnb);
  hipLaunchKernelGGL(initvecs_kernel, dim3(80), dim3(256), 0, stream, T, out, bar);
  hipLaunchKernelGGL(gemm_kernel, dim3(4, 512), dim3(256), 0, stream, z1, z2, rnorm, wnb, zc);
  {
    void* args[] = {(void*)&zc, (void*)&T, (void*)&out, (void*)&bar};
    hipLaunchCooperativeKernel((const void*)sink_kernel, dim3(256), dim3(1024),
                               args, 0, stream);
  }
}

// Round 6
// 1600.342 us; speedup vs baseline: 1.6504x; 1.6504x over previous
//
#include <hip/hip_runtime.h>
#include <hip/hip_cooperative_groups.h>
#include <stdint.h>

namespace cg = cooperative_groups;

#define NROWS 32768
#define DDIM  512
#define KDIM  512

__device__ __forceinline__ float b2f(unsigned short u) {
  return __uint_as_float(((unsigned int)u) << 16);
}
__device__ __forceinline__ unsigned short f2bf(float f) {
  unsigned int u = __float_as_uint(f);
  u += 0x7FFFu + ((u >> 16) & 1u);   // round-to-nearest-even
  return (unsigned short)(u >> 16);
}
__device__ __forceinline__ float dev_load(const float* p) {
  return __hip_atomic_load(p, __ATOMIC_RELAXED, __HIP_MEMORY_SCOPE_AGENT);
}

typedef __attribute__((ext_vector_type(8))) short bf16x8;
typedef __attribute__((ext_vector_type(4))) float f32x4;

// ---------------------------------------------------------------------------
// prep: row inverse-norms for z1/z2 (rows 0..65535) and normalized bf16 weight
// ---------------------------------------------------------------------------
__global__ __launch_bounds__(256) void prep_kernel(
    const float* __restrict__ z1, const float* __restrict__ z2,
    const float* __restrict__ w, float* __restrict__ rnorm,
    unsigned short* __restrict__ wnb) {
  const int tid = threadIdx.x;
  const int wv = tid >> 6, ln = tid & 63;
  const int row = blockIdx.x * 4 + wv;   // 0..66047
  const float* src;
  if (row < NROWS)        src = z1 + (size_t)row * DDIM;
  else if (row < 2*NROWS) src = z2 + (size_t)(row - NROWS) * DDIM;
  else                    src = w  + (size_t)(row - 2*NROWS) * DDIM;
  float4 v0 = ((const float4*)src)[ln*2];
  float4 v1 = ((const float4*)src)[ln*2+1];
  float ss = v0.x*v0.x + v0.y*v0.y + v0.z*v0.z + v0.w*v0.w
           + v1.x*v1.x + v1.y*v1.y + v1.z*v1.z + v1.w*v1.w;
  #pragma unroll
  for (int off = 1; off < 64; off <<= 1) ss += __shfl_xor(ss, off);
  float rn = 1.0f / fmaxf(sqrtf(ss), 1e-12f);
  if (row < 2*NROWS) {
    if (ln == 0) rnorm[row] = rn;
  } else {
    int r = row - 2*NROWS;
    ushort4 o0 = make_ushort4(f2bf(v0.x*rn), f2bf(v0.y*rn), f2bf(v0.z*rn), f2bf(v0.w*rn));
    ushort4 o1 = make_ushort4(f2bf(v1.x*rn), f2bf(v1.y*rn), f2bf(v1.z*rn), f2bf(v1.w*rn));
    ushort4* dst = (ushort4*)(wnb + (size_t)r*DDIM + ln*8);
    dst[0] = o0; dst[1] = o1;
  }
}

// ---------------------------------------------------------------------------
// initvecs: zero the 20 column-sum buffers (T[20][2*512]) and the output
// ---------------------------------------------------------------------------
__global__ void initvecs_kernel(float* __restrict__ T, float* __restrict__ out) {
  int i = blockIdx.x * 256 + threadIdx.x;
  if (i < 20 * 1024) T[i] = 0.f;
  if (i == 0) out[0] = 0.f;
}

// ---------------------------------------------------------------------------
// gemm: zc[r,c] = sum_d (z[r,d]*rnorm[r]) * wnb[c,d]   (bf16 MFMA, A*B^T)
// 128x128 tile, BK=32, 4 waves each 64x64 via 4x4 of 16x16x32 MFMAs
// ---------------------------------------------------------------------------
__global__ __launch_bounds__(256) void gemm_kernel(
    const float* __restrict__ z1, const float* __restrict__ z2,
    const float* __restrict__ rnorm, const unsigned short* __restrict__ wnb,
    unsigned short* __restrict__ zc) {
  constexpr int LDT = 40;   // padded LDS stride (elements): 80B rows, 16B aligned
  __shared__ unsigned short As[128 * LDT];
  __shared__ unsigned short Bs[128 * LDT];
  const int tid = threadIdx.x;
  const int colBase = blockIdx.x * 128;
  const int rowBase = blockIdx.y * 128;
  const float* Aptr = (rowBase < NROWS) ? (z1 + (size_t)rowBase * DDIM)
                                        : (z2 + (size_t)(rowBase - NROWS) * DDIM);
  const int wv = tid >> 6, ln = tid & 63;
  const int wm = wv & 1, wn = wv >> 1;
  const int lrow = ln & 15, quad = ln >> 4;

  f32x4 acc[4][4] = {};

  for (int k0 = 0; k0 < DDIM; k0 += 32) {
    // stage A (fp32 -> normalized bf16): 128 rows x 32 k
    #pragma unroll
    for (int i = 0; i < 4; i++) {
      int idx = i * 256 + tid;            // 0..1023
      int r = idx >> 3;                   // 0..127
      int kk = (idx & 7) * 4;             // 0..28
      float4 v = *(const float4*)(Aptr + (size_t)r * DDIM + k0 + kk);
      float rn = rnorm[rowBase + r];
      ushort4 o = make_ushort4(f2bf(v.x*rn), f2bf(v.y*rn), f2bf(v.z*rn), f2bf(v.w*rn));
      *(ushort4*)(&As[r * LDT + kk]) = o;
    }
    // stage B (bf16 weight): 128 rows x 32 k
    #pragma unroll
    for (int i = 0; i < 2; i++) {
      int idx = i * 256 + tid;            // 0..511
      int r = idx >> 2;                   // 0..127
      int kk = (idx & 3) * 8;             // 0..24
      float4 v = *(const float4*)(wnb + (size_t)(colBase + r) * DDIM + k0 + kk);
      *(float4*)(&Bs[r * LDT + kk]) = v;
    }
    __syncthreads();
    bf16x8 af[4], bfr[4];
    #pragma unroll
    for (int mi = 0; mi < 4; mi++)
      af[mi] = *(const bf16x8*)(&As[(64*wm + 16*mi + lrow) * LDT + quad*8]);
    #pragma unroll
    for (int ni = 0; ni < 4; ni++)
      bfr[ni] = *(const bf16x8*)(&Bs[(64*wn + 16*ni + lrow) * LDT + quad*8]);
    #pragma unroll
    for (int mi = 0; mi < 4; mi++)
      #pragma unroll
      for (int ni = 0; ni < 4; ni++)
        acc[mi][ni] = __builtin_amdgcn_mfma_f32_16x16x32_bf16(
            af[mi], bfr[ni], acc[mi][ni], 0, 0, 0);
    __syncthreads();
  }
  // epilogue: C/D layout col=lane&15, row=(lane>>4)*4+reg
  #pragma unroll
  for (int mi = 0; mi < 4; mi++)
    #pragma unroll
    for (int ni = 0; ni < 4; ni++)
      #pragma unroll
      for (int r = 0; r < 4; r++) {
        size_t grow = (size_t)rowBase + 64*wm + 16*mi + quad*4 + r;
        int gcol = colBase + 64*wn + 16*ni + lrow;
        zc[grow * KDIM + gcol] = f2bf(acc[mi][ni][r]);
      }
}

// ---------------------------------------------------------------------------
// sink2: fused 20-iteration sinkhorn + loss, single cooperative kernel,
// LDS-resident matrix 1 (compiler-proof; no VGPR-allocator dependence).
// 256 blocks x 1024 threads, 1 block/CU (forced by 132 KB dynamic LDS).
// Block b owns global rows [b*128, b*128+128) of BOTH matrices:
//   - matrix 1 rows staged once into LDS (128 x 512 bf16 = 128 KB)
//   - matrix 2 rows streamed from L3 every iteration (33.5 MB/iter grid-wide,
//     half of the 67 MB/iter a full re-read would cost), prefetched 8 rows
//     ahead of the m1 compute phase.
// Column sums: LDS Tpart[1024] via ds-atomicAdd, then one global atomic per
// thread into T[it]; grid-wide visibility via cg grid.sync() (1 per iter,
// proven functional in R2/R3). Math expressions bit-identical to the
// verified pass_kernel / loss_kernel.
// Each wave: 8 m1 rows (its own LDS writes -> no staging barrier needed)
// + 8 m2 rows; lane ln owns cols ln*8..ln*8+7.
// ---------------------------------------------------------------------------
__global__ __launch_bounds__(1024) void sink2_kernel(
    const unsigned short* __restrict__ zc,
    float* __restrict__ T, float* __restrict__ out) {
  cg::grid_group grid = cg::this_grid();
  extern __shared__ char smem[];
  unsigned short* m1 = (unsigned short*)smem;          // [128][512] bf16
  float* Tpart = (float*)(smem + 131072);              // [1024] f32
  const int tid = threadIdx.x;
  const int wv = tid >> 6, ln = tid & 63;
  const int col0 = ln * 8;
  const int lrow0 = wv * 8;                            // local m1 row base
  const size_t grow0 = (size_t)blockIdx.x * 128 + (size_t)lrow0;

  // stage matrix-1 rows into LDS (wave-private rows: no barrier needed)
  #pragma unroll
  for (int r = 0; r < 8; r++) {
    bf16x8 v = *(const bf16x8*)(zc + (grow0 + r) * KDIM + col0);
    *(bf16x8*)(&m1[(lrow0 + r) * KDIM + col0]) = v;
  }

  #pragma unroll 1
  for (int it = 0; it < 20; it++) {
    Tpart[tid] = 0.f;
    __syncthreads();
    const float* Tp = T + (size_t)(it - 1) * 1024;
    // prefetch matrix-2 rows (L3-resident; latency hidden under m1 compute)
    bf16x8 p2[8];
    #pragma unroll
    for (int r = 0; r < 8; r++)
      p2[r] = *(const bf16x8*)(zc + (grow0 + r + (size_t)NROWS) * KDIM + col0);

    // ---- matrix 1 (from LDS) ----
    {
      float a[8];
      if (it > 0) {
        #pragma unroll
        for (int j = 0; j < 8; j++) a[j] = 1.0f / (512.0f * dev_load(Tp + col0 + j));
      }
      float acc[8] = {0,0,0,0,0,0,0,0};
      #pragma unroll
      for (int r = 0; r < 8; r++) {
        bf16x8 v = *(const bf16x8*)(&m1[(lrow0 + r) * KDIM + col0]);
        float e[8];
        #pragma unroll
        for (int j = 0; j < 8; j++) e[j] = __expf(b2f((unsigned short)v[j]) * 20.f);
        if (it > 0) {
          float part = e[0]*a[0]+e[1]*a[1]+e[2]*a[2]+e[3]*a[3]
                     + e[4]*a[4]+e[5]*a[5]+e[6]*a[6]+e[7]*a[7];
          #pragma unroll
          for (int off = 1; off < 64; off <<= 1) part += __shfl_xor(part, off);
          float bb = 1.0f / (32768.0f * part);
          #pragma unroll
          for (int j = 0; j < 8; j++) acc[j] += e[j] * bb;
        } else {
          #pragma unroll
          for (int j = 0; j < 8; j++) acc[j] += e[j];
        }
      }
      #pragma unroll
      for (int j = 0; j < 8; j++) atomicAdd(&Tpart[col0 + j], acc[j]);
    }
    // ---- matrix 2 (prefetched from global) ----
    {
      float a[8];
      if (it > 0) {
        #pragma unroll
        for (int j = 0; j < 8; j++) a[j] = 1.0f / (512.0f * dev_load(Tp + 512 + col0 + j));
      }
      float acc[8] = {0,0,0,0,0,0,0,0};
      #pragma unroll
      for (int r = 0; r < 8; r++) {
        float e[8];
        #pragma unroll
        for (int j = 0; j < 8; j++) e[j] = __expf(b2f((unsigned short)p2[r][j]) * 20.f);
        if (it > 0) {
          float part = e[0]*a[0]+e[1]*a[1]+e[2]*a[2]+e[3]*a[3]
                     + e[4]*a[4]+e[5]*a[5]+e[6]*a[6]+e[7]*a[7];
          #pragma unroll
          for (int off = 1; off < 64; off <<= 1) part += __shfl_xor(part, off);
          float bb = 1.0f / (32768.0f * part);
          #pragma unroll
          for (int j = 0; j < 8; j++) acc[j] += e[j] * bb;
        } else {
          #pragma unroll
          for (int j = 0; j < 8; j++) acc[j] += e[j];
        }
      }
      #pragma unroll
      for (int j = 0; j < 8; j++) atomicAdd(&Tpart[512 + col0 + j], acc[j]);
    }
    __syncthreads();
    unsafeAtomicAdd(&T[(size_t)it * 1024 + tid], Tpart[tid]);
    grid.sync();
  }

  // ---- fused loss using T19: m1 from LDS, m2 streamed once more ----
  {
    const float* Tl = T + (size_t)19 * 1024;
    float a1[8], a2[8];
    #pragma unroll
    for (int j = 0; j < 8; j++) {
      a1[j] = 1.0f / (512.0f * dev_load(Tl + col0 + j));
      a2[j] = 1.0f / (512.0f * dev_load(Tl + 512 + col0 + j));
    }
    const float invTau = 1.0f / 0.3f;
    float part = 0.f;
    #pragma unroll 1
    for (int r = 0; r < 8; r++) {
      bf16x8 v1 = *(const bf16x8*)(&m1[(lrow0 + r) * KDIM + col0]);
      bf16x8 v2 = *(const bf16x8*)(zc + (grow0 + r + (size_t)NROWS) * KDIM + col0);
      float zf1[8], zf2[8];
      #pragma unroll
      for (int j = 0; j < 8; j++) {
        zf1[j] = b2f((unsigned short)v1[j]);
        zf2[j] = b2f((unsigned short)v2[j]);
      }
      float m1v = -1e30f, m2v = -1e30f;
      #pragma unroll
      for (int j = 0; j < 8; j++) { m1v = fmaxf(m1v, zf1[j]); m2v = fmaxf(m2v, zf2[j]); }
      #pragma unroll
      for (int off = 1; off < 64; off <<= 1) {
        m1v = fmaxf(m1v, __shfl_xor(m1v, off));
        m2v = fmaxf(m2v, __shfl_xor(m2v, off));
      }
      float se1 = 0.f, se2 = 0.f;
      #pragma unroll
      for (int j = 0; j < 8; j++) {
        se1 += __expf((zf1[j] - m1v) * invTau);
        se2 += __expf((zf2[j] - m2v) * invTau);
      }
      #pragma unroll
      for (int off = 1; off < 64; off <<= 1) {
        se1 += __shfl_xor(se1, off);
        se2 += __shfl_xor(se2, off);
      }
      float ls1 = m1v * invTau + __logf(se1);
      float ls2 = m2v * invTau + __logf(se2);
      float s1 = 0.f, n1 = 0.f, s2 = 0.f, n2 = 0.f;
      #pragma unroll
      for (int j = 0; j < 8; j++) {
        float e1 = __expf(zf1[j] * 20.f) * a1[j];
        s1 += e1; n1 += e1 * (zf2[j] * invTau - ls2);
        float e2 = __expf(zf2[j] * 20.f) * a2[j];
        s2 += e2; n2 += e2 * (zf1[j] * invTau - ls1);
      }
      #pragma unroll
      for (int off = 1; off < 64; off <<= 1) {
        s1 += __shfl_xor(s1, off); n1 += __shfl_xor(n1, off);
        s2 += __shfl_xor(s2, off); n2 += __shfl_xor(n2, off);
      }
      part += n1 / s1 + n2 / s2;
    }
    __syncthreads();                    // done with Tpart as column buffer
    if (ln == 0) Tpart[wv] = part;      // reuse LDS as 16-wave reduction buffer
    __syncthreads();
    if (tid == 0) {
      float s = 0.f;
      #pragma unroll
      for (int w = 0; w < 16; w++) s += Tpart[w];
      unsafeAtomicAdd(out, -s * (1.0f / 32768.0f));
    }
  }
}

// ---------------------------------------------------------------------------
extern "C" void kernel_launch(void* const* d_in, const int* in_sizes, int n_in,
                              void* d_out, int out_size, void* d_ws, size_t ws_size,
                              hipStream_t stream) {
  (void)in_sizes; (void)n_in; (void)out_size; (void)ws_size;
  const float* z1 = (const float*)d_in[0];
  const float* z2 = (const float*)d_in[1];
  const float* w  = (const float*)d_in[2];
  float* out = (float*)d_out;
  char* ws = (char*)d_ws;
  // workspace layout
  unsigned short* zc    = (unsigned short*)ws;                         // 67,108,864 B
  float*          rnorm = (float*)(ws + (size_t)67108864);             //    262,144 B
  unsigned short* wnb   = (unsigned short*)(ws + (size_t)67371008);    //    524,288 B
  float*          T     = (float*)(ws + (size_t)67895296);             //     81,920 B

  hipLaunchKernelGGL(prep_kernel, dim3(16512), dim3(256), 0, stream, z1, z2, w, rnorm, wnb);
  hipLaunchKernelGGL(initvecs_kernel, dim3(80), dim3(256), 0, stream, T, out);
  hipLaunchKernelGGL(gemm_kernel, dim3(4, 512), dim3(256), 0, stream, z1, z2, rnorm, wnb, zc);
  {
    static bool attr_set = false;
    if (!attr_set) {
      hipFuncSetAttribute((const void*)sink2_kernel,
                          hipFuncAttributeMaxDynamicSharedMemorySize, 135168);
      attr_set = true;
    }
    void* args[] = {(void*)&zc, (void*)&T, (void*)&out};
    hipLaunchCooperativeKernel((const void*)sink2_kernel, dim3(256), dim3(1024),
                               args, 135168, stream);
  }
}

// Round 7
// 661.686 us; speedup vs baseline: 3.9916x; 2.4186x over previous
//
#include <hip/hip_runtime.h>
#include <stdint.h>

#define NROWS 32768
#define DDIM  512
#define KDIM  512

__device__ __forceinline__ float b2f(unsigned short u) {
  return __uint_as_float(((unsigned int)u) << 16);
}
__device__ __forceinline__ unsigned short f2bf(float f) {
  unsigned int u = __float_as_uint(f);
  u += 0x7FFFu + ((u >> 16) & 1u);   // round-to-nearest-even
  return (unsigned short)(u >> 16);
}

typedef __attribute__((ext_vector_type(8))) short bf16x8;
typedef __attribute__((ext_vector_type(4))) float f32x4;

// ---------------------------------------------------------------------------
// prep: row inverse-norms for z1/z2 (rows 0..65535) and normalized bf16 weight
// ---------------------------------------------------------------------------
__global__ __launch_bounds__(256) void prep_kernel(
    const float* __restrict__ z1, const float* __restrict__ z2,
    const float* __restrict__ w, float* __restrict__ rnorm,
    unsigned short* __restrict__ wnb) {
  const int tid = threadIdx.x;
  const int wv = tid >> 6, ln = tid & 63;
  const int row = blockIdx.x * 4 + wv;   // 0..66047
  const float* src;
  if (row < NROWS)        src = z1 + (size_t)row * DDIM;
  else if (row < 2*NROWS) src = z2 + (size_t)(row - NROWS) * DDIM;
  else                    src = w  + (size_t)(row - 2*NROWS) * DDIM;
  float4 v0 = ((const float4*)src)[ln*2];
  float4 v1 = ((const float4*)src)[ln*2+1];
  float ss = v0.x*v0.x + v0.y*v0.y + v0.z*v0.z + v0.w*v0.w
           + v1.x*v1.x + v1.y*v1.y + v1.z*v1.z + v1.w*v1.w;
  #pragma unroll
  for (int off = 1; off < 64; off <<= 1) ss += __shfl_xor(ss, off);
  float rn = 1.0f / fmaxf(sqrtf(ss), 1e-12f);
  if (row < 2*NROWS) {
    if (ln == 0) rnorm[row] = rn;
  } else {
    int r = row - 2*NROWS;
    ushort4 o0 = make_ushort4(f2bf(v0.x*rn), f2bf(v0.y*rn), f2bf(v0.z*rn), f2bf(v0.w*rn));
    ushort4 o1 = make_ushort4(f2bf(v1.x*rn), f2bf(v1.y*rn), f2bf(v1.z*rn), f2bf(v1.w*rn));
    ushort4* dst = (ushort4*)(wnb + (size_t)r*DDIM + ln*8);
    dst[0] = o0; dst[1] = o1;
  }
}

// ---------------------------------------------------------------------------
// initvecs: zero the 20 column-sum buffers (T[20][2*512]) and the output
// ---------------------------------------------------------------------------
__global__ void initvecs_kernel(float* __restrict__ T, float* __restrict__ out) {
  int i = blockIdx.x * 256 + threadIdx.x;
  if (i < 20 * 1024) T[i] = 0.f;
  if (i == 0) out[0] = 0.f;
}

// ---------------------------------------------------------------------------
// gemm: zc[r,c] = sum_d (z[r,d]*rnorm[r]) * wnb[c,d]   (bf16 MFMA, A*B^T)
// 128x128 tile, BK=32, 4 waves each 64x64 via 4x4 of 16x16x32 MFMAs.
// XCD-cluster swizzle: flat 2048-block grid; with round-robin block->XCD
// dispatch (bid%8), the 4 col-blocks of each row-block land on ONE XCD in
// consecutive slots -> the A row-panel is fetched into exactly one L2 and
// reused 4x (R0 counter: FETCH 264 MB = A read into 4 different L2s).
// Fused T0 epilogue: T0[col] += sum_rows exp(bf16(acc)*20) computed from
// the exact bf16 value stored to zc -> removes the mode-0 pass entirely.
// ---------------------------------------------------------------------------
__global__ __launch_bounds__(256) void gemm_kernel(
    const float* __restrict__ z1, const float* __restrict__ z2,
    const float* __restrict__ rnorm, const unsigned short* __restrict__ wnb,
    unsigned short* __restrict__ zc, float* __restrict__ T0) {
  constexpr int LDT = 40;   // padded LDS stride (elements): 80B rows, 16B aligned
  __shared__ unsigned short As[128 * LDT];
  __shared__ unsigned short Bs[128 * LDT];
  __shared__ float colsum[128];
  const int tid = threadIdx.x;
  // XCD-cluster decode (bijective: 2048 = 8 XCDs x 64 row-blocks x 4 col-blocks)
  const int bid = blockIdx.x;
  const int xcd = bid & 7, slot = bid >> 3;
  const int rowBlk = xcd * 64 + (slot >> 2);
  const int colBlk = slot & 3;
  const int colBase = colBlk * 128;
  const int rowBase = rowBlk * 128;
  const float* Aptr = (rowBase < NROWS) ? (z1 + (size_t)rowBase * DDIM)
                                        : (z2 + (size_t)(rowBase - NROWS) * DDIM);
  const int wv = tid >> 6, ln = tid & 63;
  const int wm = wv & 1, wn = wv >> 1;
  const int lrow = ln & 15, quad = ln >> 4;

  f32x4 acc[4][4] = {};

  for (int k0 = 0; k0 < DDIM; k0 += 32) {
    // stage A (fp32 -> normalized bf16): 128 rows x 32 k
    #pragma unroll
    for (int i = 0; i < 4; i++) {
      int idx = i * 256 + tid;            // 0..1023
      int r = idx >> 3;                   // 0..127
      int kk = (idx & 7) * 4;             // 0..28
      float4 v = *(const float4*)(Aptr + (size_t)r * DDIM + k0 + kk);
      float rn = rnorm[rowBase + r];
      ushort4 o = make_ushort4(f2bf(v.x*rn), f2bf(v.y*rn), f2bf(v.z*rn), f2bf(v.w*rn));
      *(ushort4*)(&As[r * LDT + kk]) = o;
    }
    // stage B (bf16 weight): 128 rows x 32 k
    #pragma unroll
    for (int i = 0; i < 2; i++) {
      int idx = i * 256 + tid;            // 0..511
      int r = idx >> 2;                   // 0..127
      int kk = (idx & 3) * 8;             // 0..24
      float4 v = *(const float4*)(wnb + (size_t)(colBase + r) * DDIM + k0 + kk);
      *(float4*)(&Bs[r * LDT + kk]) = v;
    }
    __syncthreads();
    bf16x8 af[4], bfr[4];
    #pragma unroll
    for (int mi = 0; mi < 4; mi++)
      af[mi] = *(const bf16x8*)(&As[(64*wm + 16*mi + lrow) * LDT + quad*8]);
    #pragma unroll
    for (int ni = 0; ni < 4; ni++)
      bfr[ni] = *(const bf16x8*)(&Bs[(64*wn + 16*ni + lrow) * LDT + quad*8]);
    #pragma unroll
    for (int mi = 0; mi < 4; mi++)
      #pragma unroll
      for (int ni = 0; ni < 4; ni++)
        acc[mi][ni] = __builtin_amdgcn_mfma_f32_16x16x32_bf16(
            af[mi], bfr[ni], acc[mi][ni], 0, 0, 0);
    __syncthreads();
  }
  // epilogue: C/D layout col=lane&15, row=(lane>>4)*4+reg
  // + fused T0 column sums: exp(b2f(stored bf16)*20), bit-identical input to
  //   what the removed mode-0 pass would have read back from zc.
  if (tid < 128) colsum[tid] = 0.f;
  __syncthreads();
  #pragma unroll
  for (int ni = 0; ni < 4; ni++) {
    float s = 0.f;
    #pragma unroll
    for (int mi = 0; mi < 4; mi++)
      #pragma unroll
      for (int r = 0; r < 4; r++) {
        size_t grow = (size_t)rowBase + 64*wm + 16*mi + quad*4 + r;
        int gcol = colBase + 64*wn + 16*ni + lrow;
        unsigned short h = f2bf(acc[mi][ni][r]);
        zc[grow * KDIM + gcol] = h;
        s += __expf(b2f(h) * 20.f);
      }
    atomicAdd(&colsum[64*wn + 16*ni + lrow], s);
  }
  __syncthreads();
  if (tid < 128) {
    int matOff = (rowBase < NROWS) ? 0 : 512;
    unsafeAtomicAdd(&T0[matOff + colBase + tid], colsum[tid]);
  }
}

// ---------------------------------------------------------------------------
// sinkhorn fused pass over both matrices (16 waves/block, 8 rows/wave):
//   a_k = 1/(K*Tprev[k]); per row s = sum_k M*a; b = 1/(B*s);
//   Tnext[k] += sum_rows M[k]*b        (mode-0 now fused into gemm epilogue)
// blocks 0..255 -> matrix 0 (zc1), 256..511 -> matrix 1 (zc2)
// ---------------------------------------------------------------------------
__global__ __launch_bounds__(1024) void pass_kernel(
    const unsigned short* __restrict__ zc,
    const float* __restrict__ Tprev, float* __restrict__ Tnext, int mode) {
  __shared__ float red[16 * 512];
  const int tid = threadIdx.x;
  const int wv = tid >> 6, ln = tid & 63;
  const int gw = blockIdx.x * 16 + wv;      // 0..8191
  const size_t row0 = (size_t)gw * 8;
  const int mat = blockIdx.x >> 8;          // 0 or 1 (block-uniform)
  float a[8];
  if (mode) {
    #pragma unroll
    for (int j = 0; j < 8; j++) a[j] = 1.0f / (512.0f * Tprev[mat*512 + ln*8 + j]);
  }
  float acc[8] = {0,0,0,0,0,0,0,0};
  const unsigned short* base = zc + row0 * 512 + ln * 8;
  #pragma unroll
  for (int r = 0; r < 8; r++) {
    const ushort4* p = (const ushort4*)(base + (size_t)r * 512);
    ushort4 u0 = p[0], u1 = p[1];
    float e[8];
    e[0]=__expf(b2f(u0.x)*20.f); e[1]=__expf(b2f(u0.y)*20.f);
    e[2]=__expf(b2f(u0.z)*20.f); e[3]=__expf(b2f(u0.w)*20.f);
    e[4]=__expf(b2f(u1.x)*20.f); e[5]=__expf(b2f(u1.y)*20.f);
    e[6]=__expf(b2f(u1.z)*20.f); e[7]=__expf(b2f(u1.w)*20.f);
    if (mode) {
      float part = e[0]*a[0]+e[1]*a[1]+e[2]*a[2]+e[3]*a[3]
                 + e[4]*a[4]+e[5]*a[5]+e[6]*a[6]+e[7]*a[7];
      #pragma unroll
      for (int off = 1; off < 64; off <<= 1) part += __shfl_xor(part, off);
      float b = 1.0f / (32768.0f * part);
      #pragma unroll
      for (int j = 0; j < 8; j++) acc[j] += e[j] * b;
    } else {
      #pragma unroll
      for (int j = 0; j < 8; j++) acc[j] += e[j];
    }
  }
  #pragma unroll
  for (int j = 0; j < 8; j++) red[wv*512 + ln*8 + j] = acc[j];
  __syncthreads();
  if (tid < 512) {
    float s = 0.f;
    #pragma unroll
    for (int w = 0; w < 16; w++) s += red[w*512 + tid];
    unsafeAtomicAdd(&Tnext[mat*512 + tid], s);
  }
}

// ---------------------------------------------------------------------------
// loss: a20 = 1/(K*T19); per row: q = M*a/s (s = sum_k M*a);
// logp = z/tau - logsumexp(z/tau);  out -= (sum_k q1*logp2 + q2*logp1)/N
// 16 waves/block, 4 rows/wave, 512 blocks
// ---------------------------------------------------------------------------
__global__ __launch_bounds__(1024) void loss_kernel(
    const unsigned short* __restrict__ zc,
    const float* __restrict__ T19, float* __restrict__ out) {
  const int tid = threadIdx.x;
  const int wv = tid >> 6, ln = tid & 63;
  const int gw = blockIdx.x * 16 + wv;      // 0..8191
  const size_t row0 = (size_t)gw * 4;
  float a1[8], a2[8];
  #pragma unroll
  for (int j = 0; j < 8; j++) {
    a1[j] = 1.0f / (512.0f * T19[ln*8 + j]);
    a2[j] = 1.0f / (512.0f * T19[512 + ln*8 + j]);
  }
  const float invTau = 1.0f / 0.3f;
  float part = 0.f;
  for (int r = 0; r < 4; r++) {
    size_t b = row0 + r;
    const ushort4* p1 = (const ushort4*)(zc + b * 512 + ln * 8);
    const ushort4* p2 = (const ushort4*)(zc + (b + NROWS) * 512 + ln * 8);
    ushort4 u10 = p1[0], u11 = p1[1], u20 = p2[0], u21 = p2[1];
    float zf1[8], zf2[8];
    zf1[0]=b2f(u10.x); zf1[1]=b2f(u10.y); zf1[2]=b2f(u10.z); zf1[3]=b2f(u10.w);
    zf1[4]=b2f(u11.x); zf1[5]=b2f(u11.y); zf1[6]=b2f(u11.z); zf1[7]=b2f(u11.w);
    zf2[0]=b2f(u20.x); zf2[1]=b2f(u20.y); zf2[2]=b2f(u20.z); zf2[3]=b2f(u20.w);
    zf2[4]=b2f(u21.x); zf2[5]=b2f(u21.y); zf2[6]=b2f(u21.z); zf2[7]=b2f(u21.w);
    float m1 = -1e30f, m2 = -1e30f;
    #pragma unroll
    for (int j = 0; j < 8; j++) { m1 = fmaxf(m1, zf1[j]); m2 = fmaxf(m2, zf2[j]); }
    #pragma unroll
    for (int off = 1; off < 64; off <<= 1) {
      m1 = fmaxf(m1, __shfl_xor(m1, off));
      m2 = fmaxf(m2, __shfl_xor(m2, off));
    }
    float se1 = 0.f, se2 = 0.f;
    #pragma unroll
    for (int j = 0; j < 8; j++) {
      se1 += __expf((zf1[j] - m1) * invTau);
      se2 += __expf((zf2[j] - m2) * invTau);
    }
    #pragma unroll
    for (int off = 1; off < 64; off <<= 1) {
      se1 += __shfl_xor(se1, off);
      se2 += __shfl_xor(se2, off);
    }
    float ls1 = m1 * invTau + __logf(se1);
    float ls2 = m2 * invTau + __logf(se2);
    float s1 = 0.f, n1 = 0.f, s2 = 0.f, n2 = 0.f;
    #pragma unroll
    for (int j = 0; j < 8; j++) {
      float e1 = __expf(zf1[j] * 20.f) * a1[j];
      s1 += e1; n1 += e1 * (zf2[j] * invTau - ls2);
      float e2 = __expf(zf2[j] * 20.f) * a2[j];
      s2 += e2; n2 += e2 * (zf1[j] * invTau - ls1);
    }
    #pragma unroll
    for (int off = 1; off < 64; off <<= 1) {
      s1 += __shfl_xor(s1, off); n1 += __shfl_xor(n1, off);
      s2 += __shfl_xor(s2, off); n2 += __shfl_xor(n2, off);
    }
    part += n1 / s1 + n2 / s2;
  }
  __shared__ float red[16];
  if (ln == 0) red[wv] = part;
  __syncthreads();
  if (tid == 0) {
    float s = 0.f;
    #pragma unroll
    for (int w = 0; w < 16; w++) s += red[w];
    unsafeAtomicAdd(out, -s * (1.0f / 32768.0f));
  }
}

// ---------------------------------------------------------------------------
extern "C" void kernel_launch(void* const* d_in, const int* in_sizes, int n_in,
                              void* d_out, int out_size, void* d_ws, size_t ws_size,
                              hipStream_t stream) {
  (void)in_sizes; (void)n_in; (void)out_size; (void)ws_size;
  const float* z1 = (const float*)d_in[0];
  const float* z2 = (const float*)d_in[1];
  const float* w  = (const float*)d_in[2];
  float* out = (float*)d_out;
  char* ws = (char*)d_ws;
  // workspace layout
  unsigned short* zc    = (unsigned short*)ws;                         // 67,108,864 B
  float*          rnorm = (float*)(ws + (size_t)67108864);             //    262,144 B
  unsigned short* wnb   = (unsigned short*)(ws + (size_t)67371008);    //    524,288 B
  float*          T     = (float*)(ws + (size_t)67895296);             //     81,920 B

  hipLaunchKernelGGL(prep_kernel, dim3(16512), dim3(256), 0, stream, z1, z2, w, rnorm, wnb);
  hipLaunchKernelGGL(initvecs_kernel, dim3(80), dim3(256), 0, stream, T, out);
  hipLaunchKernelGGL(gemm_kernel, dim3(2048), dim3(256), 0, stream, z1, z2, rnorm, wnb, zc, T);
  for (int i = 1; i < 20; i++)
    hipLaunchKernelGGL(pass_kernel, dim3(512), dim3(1024), 0, stream,
                       zc, T + (size_t)(i-1)*1024, T + (size_t)i*1024, 1);
  hipLaunchKernelGGL(loss_kernel, dim3(512), dim3(1024), 0, stream, zc, T + 19*1024, out);
}